// Round 8
// baseline (182.904 us; speedup 1.0000x reference)
//
#include <hip/hip_runtime.h>
#include <hip/hip_bf16.h>

typedef __bf16 bf16;
typedef __bf16 bf16x8 __attribute__((ext_vector_type(8)));
typedef __bf16 bf16x4 __attribute__((ext_vector_type(4)));
typedef float f32x4 __attribute__((ext_vector_type(4)));
typedef float f32x16 __attribute__((ext_vector_type(16)));
typedef unsigned int u32x4 __attribute__((ext_vector_type(4)));

constexpr int DM = 1024, NH = 16, DH = 64, NB = 2, SQ = 2048;
constexpr int MTOT = NB * SQ;  // 4096
// Q is pre-scaled by 1/sqrt(DH) * log2(e) so attn does bare exp2(S).
constexpr float QSCALE = 0.125f * 1.44269504088896f;

// async global->LDS, 16B per lane; LDS dest is wave-uniform base + lane*16 (HW rule)
__device__ __forceinline__ void gld_lds16(const bf16* g, bf16* l) {
  __builtin_amdgcn_global_load_lds(
      (const __attribute__((address_space(1))) void*)g,
      (__attribute__((address_space(3))) void*)l, 16, 0, 0);
}

// ============ fp32 -> bf16 conversion: 4x W (1M elts each) + x (4M elts) ============
// Flat grid: 8192 blocks x 256 thr x 4 elts = 8M elems exactly (no dead blocks).
__global__ __launch_bounds__(256) void cvt5(
    const float* __restrict__ s0, const float* __restrict__ s1,
    const float* __restrict__ s2, const float* __restrict__ s3,
    const float* __restrict__ s4,
    bf16* __restrict__ d0, bf16* __restrict__ d1, bf16* __restrict__ d2,
    bf16* __restrict__ d3, bf16* __restrict__ d4) {
  const int idx = (blockIdx.x * 256 + threadIdx.x) * 4;
  const float* src; bf16* dst; int off;
  if (idx < 4 * DM * DM) {               // DM*DM == 2^20
    off = idx & (DM * DM - 1);
    switch (idx >> 20) {
      case 0: src = s0; dst = d0; break;
      case 1: src = s1; dst = d1; break;
      case 2: src = s2; dst = d2; break;
      default: src = s3; dst = d3; break;
    }
  } else {
    src = s4; dst = d4; off = idx - 4 * DM * DM;
  }
  const float4 v = *(const float4*)(src + off);
  *(bf16x4*)(dst + off) = (bf16x4){(bf16)v.x, (bf16)v.y, (bf16)v.z, (bf16)v.w};
}

// ======== GEMM-NT tile body (single-buffered, m97-proven): qkv only ========
// 128x128 tile, BK=64, 256 threads (4 waves), 32 KB LDS.
// m97 family: this body compiles to ~164 VGPR -> NATURAL occupancy 3 blocks/CU.
// R7 FIX: launch_bounds min-waves 4 -> 3. The (256,4) bound capped VGPR at 128,
// ~36 under the body's natural footprint -> spill-to-scratch in the K-loop.
// LDS XOR-swizzled: 16B-chunk c of row r at slot c^(r&7) -> ds_read_b128 conflict-free.
template <typename OutT>
__device__ __forceinline__ void gemm_tile128(
    const bf16* __restrict__ A, const bf16* __restrict__ Bm,
    const float* __restrict__ bias, OutT* __restrict__ C,
    int rowA0, int rowB0, int N, int K, bool bias_row, float cscale,
    bf16* sA, bf16* sB) {
  const int tid = threadIdx.x;
  const int wave = tid >> 6, lane = tid & 63;
  const int quad = lane >> 4, l16 = lane & 15;
  const int row0w = (wave >> 1) * 64;
  const int col0w = (wave & 1) * 64;

  f32x4 acc[4][4];
#pragma unroll
  for (int i = 0; i < 4; i++)
#pragma unroll
    for (int j = 0; j < 4; j++) acc[i][j] = (f32x4){0.f, 0.f, 0.f, 0.f};

  const int srow = lane >> 3;                         // 0..7
  const int scol = ((lane & 7) ^ srow) * 8;           // swizzled global chunk

  for (int kt = 0; kt < K; kt += 64) {
#pragma unroll
    for (int i = 0; i < 4; i++) {
      const int r = i * 32 + wave * 8;
      gld_lds16(A + (size_t)(rowA0 + r + srow) * K + kt + scol, &sA[r * 64]);
      gld_lds16(Bm + (size_t)(rowB0 + r + srow) * K + kt + scol, &sB[r * 64]);
    }
    __syncthreads();  // drains vmcnt for global_load_lds
#pragma unroll
    for (int kk = 0; kk < 64; kk += 32) {
      bf16x8 aF[4], bF[4];
      const int slot = (((kk >> 3) + quad) ^ (l16 & 7)) << 3;
#pragma unroll
      for (int mt = 0; mt < 4; mt++)
        aF[mt] = *(const bf16x8*)&sA[(row0w + mt * 16 + l16) * 64 + slot];
#pragma unroll
      for (int nt = 0; nt < 4; nt++)
        bF[nt] = *(const bf16x8*)&sB[(col0w + nt * 16 + l16) * 64 + slot];
#pragma unroll
      for (int mt = 0; mt < 4; mt++)
#pragma unroll
        for (int nt = 0; nt < 4; nt++)
          acc[mt][nt] = __builtin_amdgcn_mfma_f32_16x16x32_bf16(aF[mt], bF[nt], acc[mt][nt], 0, 0, 0);
    }
    __syncthreads();
  }

  // epilogue: C/D layout col=lane&15, row=quad*4+reg (verified m89/m91)
#pragma unroll
  for (int mt = 0; mt < 4; mt++) {
#pragma unroll
    for (int nt = 0; nt < 4; nt++) {
#pragma unroll
      for (int r = 0; r < 4; r++) {
        const int row = rowA0 + row0w + mt * 16 + quad * 4 + r;
        const int col = rowB0 + col0w + nt * 16 + l16;
        const float bb = bias_row ? bias[row] : bias[col];
        C[(size_t)row * N + col] = (OutT)((acc[mt][nt][r] + bb) * cscale);
      }
    }
  }
}

// Fused Q/K/V^T projection: grid (32, 8, 3). z=0 -> Q (pre-scaled), z=1 -> K, z=2 -> V^T.
// R7: launch_bounds (256,3) — m97's measured config (164 VGPR, 3 blocks/CU, no spill).
__global__ __launch_bounds__(256, 3) void qkv_gemm(
    const bf16* __restrict__ xb, const bf16* __restrict__ Wqb,
    const bf16* __restrict__ Wkb, const bf16* __restrict__ Wvb,
    const float* __restrict__ bq, const float* __restrict__ bk,
    const float* __restrict__ bv,
    bf16* __restrict__ Qw, bf16* __restrict__ Kw, bf16* __restrict__ VTw) {
  __shared__ alignas(16) bf16 sA[128 * 64];
  __shared__ alignas(16) bf16 sB[128 * 64];
  if (blockIdx.z == 0) {
    gemm_tile128<bf16>(xb, Wqb, bq, Qw, blockIdx.x * 128, blockIdx.y * 128, DM, DM, false, QSCALE, sA, sB);
  } else if (blockIdx.z == 1) {
    gemm_tile128<bf16>(xb, Wkb, bk, Kw, blockIdx.x * 128, blockIdx.y * 128, DM, DM, false, 1.0f, sA, sB);
  } else {
    // VT[n][m] = sum_k Wv[n][k] x[m][k] + bv[n]  (swapped operands -> V^T layout directly)
    const int id = blockIdx.y * 32 + blockIdx.x;  // 0..255
    gemm_tile128<bf16>(Wvb, xb, bv, VTw, (id >> 5) * 128, (id & 31) * 128, MTOT, DM, true, 1.0f, sA, sB);
  }
}

// ======== Output projection (R6): double-buffered prefetch K-loop, 1 barrier/step ========
// 64x128 tile, 512 blocks, LDS 48 KB dbuf -> 3 blocks/CU. stage(t+1) in flight during
// compute(t); measured ~-2 us vs single-buffered (R6).
__global__ __launch_bounds__(256, 3) void out_gemm(
    const bf16* __restrict__ A, const bf16* __restrict__ Bm,
    const float* __restrict__ bias, float* __restrict__ C) {
  __shared__ alignas(16) bf16 sA[2][64 * 64];
  __shared__ alignas(16) bf16 sB[2][128 * 64];
  const int tid = threadIdx.x;
  const int wave = tid >> 6, lane = tid & 63;
  const int quad = lane >> 4, l16 = lane & 15;
  const int col0w = wave * 32;
  const int rowA0 = blockIdx.x * 64, rowB0 = blockIdx.y * 128;

  f32x4 acc[4][2];
#pragma unroll
  for (int i = 0; i < 4; i++)
#pragma unroll
    for (int j = 0; j < 2; j++) acc[i][j] = (f32x4){0.f, 0.f, 0.f, 0.f};

  const int srow = lane >> 3;
  const int scol = ((lane & 7) ^ srow) * 8;

  auto stage = [&](int kt, int buf) {
#pragma unroll
    for (int i = 0; i < 2; i++) {
      const int r = i * 32 + wave * 8;
      gld_lds16(A + (size_t)(rowA0 + r + srow) * DM + kt * 64 + scol, &sA[buf][r * 64]);
    }
#pragma unroll
    for (int i = 0; i < 4; i++) {
      const int r = i * 32 + wave * 8;
      gld_lds16(Bm + (size_t)(rowB0 + r + srow) * DM + kt * 64 + scol, &sB[buf][r * 64]);
    }
  };

  stage(0, 0);
  for (int t = 0; t < 16; ++t) {
    __syncthreads();  // buf[t&1] loads complete; buf[t^1] free to overwrite
    if (t + 1 < 16) stage(t + 1, (t + 1) & 1);
    const bf16* cA = sA[t & 1];
    const bf16* cB = sB[t & 1];
#pragma unroll
    for (int kk = 0; kk < 64; kk += 32) {
      bf16x8 aF[4], bF[2];
      const int slot = (((kk >> 3) + quad) ^ (l16 & 7)) << 3;
#pragma unroll
      for (int mt = 0; mt < 4; mt++)
        aF[mt] = *(const bf16x8*)&cA[(mt * 16 + l16) * 64 + slot];
#pragma unroll
      for (int nt = 0; nt < 2; nt++)
        bF[nt] = *(const bf16x8*)&cB[(col0w + nt * 16 + l16) * 64 + slot];
#pragma unroll
      for (int mt = 0; mt < 4; mt++)
#pragma unroll
        for (int nt = 0; nt < 2; nt++)
          acc[mt][nt] = __builtin_amdgcn_mfma_f32_16x16x32_bf16(aF[mt], bF[nt], acc[mt][nt], 0, 0, 0);
    }
  }

#pragma unroll
  for (int mt = 0; mt < 4; mt++) {
#pragma unroll
    for (int nt = 0; nt < 2; nt++) {
#pragma unroll
      for (int r = 0; r < 4; r++) {
        const int row = rowA0 + mt * 16 + quad * 4 + r;
        const int col = rowB0 + col0w + nt * 16 + l16;
        C[(size_t)row * DM + col] = acc[mt][nt][r] + bias[col];
      }
    }
  }
}

// ============ Flash attention v3 (final): 32x32 MFMA + in-register softmax ============
// Proven 48.7-49.2 us / ~700 TF. Structure experiments all neutral-to-worse:
// R1 smaller tile (58), R4 V-direct-L2 (75), R5 in-block KV-split 2x occ (49.0),
// R7 QBLK=256 8-wave share (53.4) -> v3 is the local optimum of this family.
// grid (32 hb, 16 qt) = 512 blocks -> 2 blocks/CU; K+V per (b,h) 512 KB, 4 hb/XCD ->
// 2 MB < 4 MB L2 (hb = linear-id mod 8 pins XCD).
__global__ __launch_bounds__(256, 2) void attn(
    const bf16* __restrict__ Q, const bf16* __restrict__ Kq,
    const bf16* __restrict__ VT, bf16* __restrict__ O) {
  __shared__ alignas(16) bf16 sK[2][64 * 64];
  __shared__ alignas(16) bf16 sV[2][64 * 64];   // V^T tile: [dh=64][seq 64]
  const int tid = threadIdx.x, wave = tid >> 6, lane = tid & 63;
  const int l32 = lane & 31, half = lane >> 5;
  const int hb = blockIdx.x, qt = blockIdx.y;
  const int h = hb & 15, b = hb >> 4;

  const bf16* Qg = Q + (size_t)(b * SQ + qt * 128 + wave * 32) * DM + h * DH;
  const bf16* Kg = Kq + (size_t)(b * SQ) * DM + h * DH;
  const bf16* Vg = VT + (size_t)(h * DH) * MTOT + b * SQ;

  const int srow = lane >> 3, scol = ((lane & 7) ^ srow) * 8;   // 64-wide rows, swizzled

  auto stageKV = [&](int t, int buf) {
#pragma unroll
    for (int i = 0; i < 2; i++) {
      const int r = (wave * 2 + i) * 8;
      gld_lds16(Kg + (size_t)(t * 64 + r + srow) * DM + scol, &sK[buf][r * 64]);
      gld_lds16(Vg + (size_t)(r + srow) * MTOT + t * 64 + scol, &sV[buf][r * 64]);
    }
  };

  // Q as MFMA B-fragment: n=q=lane&31 (row of Q), k = kk*16 + half*8 + j (contiguous 16B)
  bf16x8 qF[4];
#pragma unroll
  for (int kk = 0; kk < 4; kk++)
    qF[kk] = *(const bf16x8*)(Qg + (size_t)l32 * DM + kk * 16 + half * 8);

  f32x16 o_acc[2];
#pragma unroll
  for (int nd = 0; nd < 2; nd++)
#pragma unroll
    for (int i = 0; i < 16; i++) o_acc[nd][i] = 0.f;
  f32x4 lsum4 = (f32x4){0.f, 0.f, 0.f, 0.f};

  stageKV(0, 0);
  for (int t = 0; t < 32; ++t) {
    __syncthreads();  // sK/sV[t&1] ready (staged during t-1's compute)
    if (t + 1 < 32) stageKV(t + 1, (t + 1) & 1);
    const bf16* cK = sK[t & 1];
    const bf16* cV = sV[t & 1];
    const int sw7 = l32 & 7;  // LDS swizzle row bits (row&7 == l32&7 for 32-aligned rows)

    // ---- S^T = K*Q^T: A = K[kv-block 32][k 16] from LDS, B = qF (registers) ----
    f32x16 sacc[2];
#pragma unroll
    for (int nt = 0; nt < 2; nt++)
#pragma unroll
      for (int i = 0; i < 16; i++) sacc[nt][i] = 0.f;

    bf16x8 kf[2][4];
#pragma unroll
    for (int nt = 0; nt < 2; nt++)
#pragma unroll
      for (int kk = 0; kk < 4; kk++)
        kf[nt][kk] = *(const bf16x8*)&cK[(nt * 32 + l32) * 64 + (((kk * 2 + half) ^ sw7) << 3)];
    __builtin_amdgcn_s_setprio(1);
#pragma unroll
    for (int nt = 0; nt < 2; nt++)
#pragma unroll
      for (int kk = 0; kk < 4; kk++)
        sacc[nt] = __builtin_amdgcn_mfma_f32_32x32x16_bf16(kf[nt][kk], qF[kk], sacc[nt], 0, 0, 0);
    __builtin_amdgcn_s_setprio(0);

    // ---- per kv-block: exp2 + in-register P pack (T12) + PV ----
#pragma unroll
    for (int nt = 0; nt < 2; nt++) {
      float p[16];
#pragma unroll
      for (int i = 0; i < 16; i++) {
        p[i] = __builtin_amdgcn_exp2f(sacc[nt][i]);
        lsum4[i & 3] += p[i];   // 4 parallel dep chains
      }
      unsigned int w[8];
#pragma unroll
      for (int i = 0; i < 8; i++)
        asm("v_cvt_pk_bf16_f32 %0, %1, %2" : "=v"(w[i]) : "v"(p[2 * i]), "v"(p[2 * i + 1]));
      // swap pairs (w0,w2),(w1,w3): words land IN ORDER as B-frag of k-step 2*nt;
      // (w4,w6),(w5,w7) -> k-step 2*nt+1.  (verified lane map R3)
      asm("v_permlane32_swap_b32 %0, %1" : "+v"(w[0]), "+v"(w[2]));
      asm("v_permlane32_swap_b32 %0, %1" : "+v"(w[1]), "+v"(w[3]));
      asm("v_permlane32_swap_b32 %0, %1" : "+v"(w[4]), "+v"(w[6]));
      asm("v_permlane32_swap_b32 %0, %1" : "+v"(w[5]), "+v"(w[7]));
#pragma unroll
      for (int s = 0; s < 2; s++) {
        const u32x4 pw = (s == 0) ? (u32x4){w[0], w[1], w[2], w[3]}
                                  : (u32x4){w[4], w[5], w[6], w[7]};
        const bf16x8 pb = __builtin_bit_cast(bf16x8, pw);
        const int ks = nt * 2 + s;  // kv k-step 0..3 within the 64-kv tile
        bf16x8 vf[2];
#pragma unroll
        for (int nd = 0; nd < 2; nd++)
          vf[nd] = *(const bf16x8*)&cV[(nd * 32 + l32) * 64 + (((ks * 2 + half) ^ sw7) << 3)];
        __builtin_amdgcn_s_setprio(1);
#pragma unroll
        for (int nd = 0; nd < 2; nd++)
          o_acc[nd] = __builtin_amdgcn_mfma_f32_32x32x16_bf16(vf[nd], pb, o_acc[nd], 0, 0, 0);
        __builtin_amdgcn_s_setprio(0);
      }
    }
  }

  // l[q] = own-half partial + other-half partial (lane^32 holds same q, other kv half)
  const float lsum = (lsum4[0] + lsum4[1]) + (lsum4[2] + lsum4[3]);
  const float lother = __shfl(lsum, lane ^ 32, 64);
  const float inv = 1.0f / (lsum + lother);

  // O^T C-layout: lane holds col q=l32 (one O row!), d = nd*32 + 8*g + 4*half + r
  bf16* Op = O + (size_t)(b * SQ + qt * 128 + wave * 32 + l32) * DM + h * DH;
#pragma unroll
  for (int nd = 0; nd < 2; nd++) {
#pragma unroll
    for (int g = 0; g < 4; g++) {
      bf16x4 ov;
#pragma unroll
      for (int r = 0; r < 4; r++) ov[r] = (bf16)(o_acc[nd][g * 4 + r] * inv);
      *(bf16x4*)(Op + nd * 32 + g * 8 + half * 4) = ov;
    }
  }
}

extern "C" void kernel_launch(void* const* d_in, const int* in_sizes, int n_in,
                              void* d_out, int out_size, void* d_ws, size_t ws_size,
                              hipStream_t stream) {
  // Reference dtypes: ALL inputs float32, output float32. Internal compute bf16.
  const float* x  = (const float*)d_in[0];
  const float* Wq = (const float*)d_in[1];
  const float* bq = (const float*)d_in[2];
  const float* Wk = (const float*)d_in[3];
  const float* bk = (const float*)d_in[4];
  const float* Wv = (const float*)d_in[5];
  const float* bv = (const float*)d_in[6];
  const float* Wo = (const float*)d_in[7];
  const float* bo = (const float*)d_in[8];
  float* out = (float*)d_out;

  bf16* ws   = (bf16*)d_ws;
  bf16* xb   = ws;                          // [4096][1024]
  bf16* Wqb  = ws + (size_t)MTOT * DM;
  bf16* Wkb  = Wqb + (size_t)DM * DM;
  bf16* Wvb  = Wkb + (size_t)DM * DM;
  bf16* Wob  = Wvb + (size_t)DM * DM;
  bf16* Qw   = Wob + (size_t)DM * DM;       // [4096][1024]  (pre-scaled by QSCALE)
  bf16* Kw   = Qw + (size_t)MTOT * DM;      // [4096][1024]
  bf16* VTw  = Kw + (size_t)MTOT * DM;      // [1024][4096]  (V transposed)
  bf16* Cw   = VTw + (size_t)MTOT * DM;     // [4096][1024]  (context)

  const dim3 blk(256);
  // 8192 blocks x 256 thr x 4 elts == 8M elems exactly (4 x 1M weights + 4M x)
  cvt5<<<dim3((4 * DM * DM + MTOT * DM) / 1024, 1), blk, 0, stream>>>(
      Wq, Wk, Wv, Wo, x, Wqb, Wkb, Wvb, Wob, xb);
  qkv_gemm<<<dim3(32, 8, 3), blk, 0, stream>>>(xb, Wqb, Wkb, Wvb, bq, bk, bv, Qw, Kw, VTw);
  attn<<<dim3(NH * NB, SQ / 128), blk, 0, stream>>>(Qw, Kw, VTw, Cw);
  out_gemm<<<dim3(MTOT / 64, DM / 128), blk, 0, stream>>>(Cw, Wob, bo, out);
}

// Round 9
// 181.109 us; speedup vs baseline: 1.0099x; 1.0099x over previous
//
#include <hip/hip_runtime.h>
#include <hip/hip_bf16.h>

typedef __bf16 bf16;
typedef __bf16 bf16x8 __attribute__((ext_vector_type(8)));
typedef __bf16 bf16x4 __attribute__((ext_vector_type(4)));
typedef float f32x4 __attribute__((ext_vector_type(4)));
typedef float f32x16 __attribute__((ext_vector_type(16)));
typedef unsigned int u32x4 __attribute__((ext_vector_type(4)));

constexpr int DM = 1024, NH = 16, DH = 64, NB = 2, SQ = 2048;
constexpr int MTOT = NB * SQ;  // 4096
// Q is pre-scaled by 1/sqrt(DH) * log2(e) so attn does bare exp2(S).
constexpr float QSCALE = 0.125f * 1.44269504088896f;

// async global->LDS, 16B per lane; LDS dest is wave-uniform base + lane*16 (HW rule)
__device__ __forceinline__ void gld_lds16(const bf16* g, bf16* l) {
  __builtin_amdgcn_global_load_lds(
      (const __attribute__((address_space(1))) void*)g,
      (__attribute__((address_space(3))) void*)l, 16, 0, 0);
}

// ============ fp32 -> bf16 conversion: 4x W (1M elts each) + x (4M elts) ============
// R8: 8 elems/thread (2x float4 read + one 16B bf16x8 store = full-width coalescing).
// 4096 blocks x 256 thr x 8 = 8M elems exactly; W arrays = 512 blocks each, no straddle.
__global__ __launch_bounds__(256) void cvt5(
    const float* __restrict__ s0, const float* __restrict__ s1,
    const float* __restrict__ s2, const float* __restrict__ s3,
    const float* __restrict__ s4,
    bf16* __restrict__ d0, bf16* __restrict__ d1, bf16* __restrict__ d2,
    bf16* __restrict__ d3, bf16* __restrict__ d4) {
  const int idx = (blockIdx.x * 256 + threadIdx.x) * 8;
  const float* src; bf16* dst; int off;
  if (idx < 4 * DM * DM) {               // DM*DM == 2^20
    off = idx & (DM * DM - 1);
    switch (idx >> 20) {
      case 0: src = s0; dst = d0; break;
      case 1: src = s1; dst = d1; break;
      case 2: src = s2; dst = d2; break;
      default: src = s3; dst = d3; break;
    }
  } else {
    src = s4; dst = d4; off = idx - 4 * DM * DM;
  }
  const float4 a = *(const float4*)(src + off);
  const float4 b = *(const float4*)(src + off + 4);
  *(bf16x8*)(dst + off) = (bf16x8){(bf16)a.x, (bf16)a.y, (bf16)a.z, (bf16)a.w,
                                   (bf16)b.x, (bf16)b.y, (bf16)b.z, (bf16)b.w};
}

// ======== GEMM-NT tile body (single-buffered, m97-proven): qkv only ========
// 128x128 tile, BK=64, 256 threads (4 waves), 32 KB LDS.
// R8 post-mortem: (256,3) vs (256,4) measured neutral-to-worse -> restore (256,4),
// the best-measured config (R6: 179.9 us total). No spill signal.
// LDS XOR-swizzled: 16B-chunk c of row r at slot c^(r&7) -> ds_read_b128 conflict-free.
template <typename OutT>
__device__ __forceinline__ void gemm_tile128(
    const bf16* __restrict__ A, const bf16* __restrict__ Bm,
    const float* __restrict__ bias, OutT* __restrict__ C,
    int rowA0, int rowB0, int N, int K, bool bias_row, float cscale,
    bf16* sA, bf16* sB) {
  const int tid = threadIdx.x;
  const int wave = tid >> 6, lane = tid & 63;
  const int quad = lane >> 4, l16 = lane & 15;
  const int row0w = (wave >> 1) * 64;
  const int col0w = (wave & 1) * 64;

  f32x4 acc[4][4];
#pragma unroll
  for (int i = 0; i < 4; i++)
#pragma unroll
    for (int j = 0; j < 4; j++) acc[i][j] = (f32x4){0.f, 0.f, 0.f, 0.f};

  const int srow = lane >> 3;                         // 0..7
  const int scol = ((lane & 7) ^ srow) * 8;           // swizzled global chunk

  for (int kt = 0; kt < K; kt += 64) {
#pragma unroll
    for (int i = 0; i < 4; i++) {
      const int r = i * 32 + wave * 8;
      gld_lds16(A + (size_t)(rowA0 + r + srow) * K + kt + scol, &sA[r * 64]);
      gld_lds16(Bm + (size_t)(rowB0 + r + srow) * K + kt + scol, &sB[r * 64]);
    }
    __syncthreads();  // drains vmcnt for global_load_lds
#pragma unroll
    for (int kk = 0; kk < 64; kk += 32) {
      bf16x8 aF[4], bF[4];
      const int slot = (((kk >> 3) + quad) ^ (l16 & 7)) << 3;
#pragma unroll
      for (int mt = 0; mt < 4; mt++)
        aF[mt] = *(const bf16x8*)&sA[(row0w + mt * 16 + l16) * 64 + slot];
#pragma unroll
      for (int nt = 0; nt < 4; nt++)
        bF[nt] = *(const bf16x8*)&sB[(col0w + nt * 16 + l16) * 64 + slot];
#pragma unroll
      for (int mt = 0; mt < 4; mt++)
#pragma unroll
        for (int nt = 0; nt < 4; nt++)
          acc[mt][nt] = __builtin_amdgcn_mfma_f32_16x16x32_bf16(aF[mt], bF[nt], acc[mt][nt], 0, 0, 0);
    }
    __syncthreads();
  }

  // epilogue: C/D layout col=lane&15, row=quad*4+reg (verified m89/m91)
#pragma unroll
  for (int mt = 0; mt < 4; mt++) {
#pragma unroll
    for (int nt = 0; nt < 4; nt++) {
#pragma unroll
      for (int r = 0; r < 4; r++) {
        const int row = rowA0 + row0w + mt * 16 + quad * 4 + r;
        const int col = rowB0 + col0w + nt * 16 + l16;
        const float bb = bias_row ? bias[row] : bias[col];
        C[(size_t)row * N + col] = (OutT)((acc[mt][nt][r] + bb) * cscale);
      }
    }
  }
}

// Fused Q/K/V^T projection: grid (32, 8, 3). z=0 -> Q (pre-scaled), z=1 -> K, z=2 -> V^T.
// (256,4) = best-measured config (R6).
__global__ __launch_bounds__(256, 4) void qkv_gemm(
    const bf16* __restrict__ xb, const bf16* __restrict__ Wqb,
    const bf16* __restrict__ Wkb, const bf16* __restrict__ Wvb,
    const float* __restrict__ bq, const float* __restrict__ bk,
    const float* __restrict__ bv,
    bf16* __restrict__ Qw, bf16* __restrict__ Kw, bf16* __restrict__ VTw) {
  __shared__ alignas(16) bf16 sA[128 * 64];
  __shared__ alignas(16) bf16 sB[128 * 64];
  if (blockIdx.z == 0) {
    gemm_tile128<bf16>(xb, Wqb, bq, Qw, blockIdx.x * 128, blockIdx.y * 128, DM, DM, false, QSCALE, sA, sB);
  } else if (blockIdx.z == 1) {
    gemm_tile128<bf16>(xb, Wkb, bk, Kw, blockIdx.x * 128, blockIdx.y * 128, DM, DM, false, 1.0f, sA, sB);
  } else {
    // VT[n][m] = sum_k Wv[n][k] x[m][k] + bv[n]  (swapped operands -> V^T layout directly)
    const int id = blockIdx.y * 32 + blockIdx.x;  // 0..255
    gemm_tile128<bf16>(Wvb, xb, bv, VTw, (id >> 5) * 128, (id & 31) * 128, MTOT, DM, true, 1.0f, sA, sB);
  }
}

// ======== Output projection (R6): double-buffered prefetch K-loop, 1 barrier/step ========
// 64x128 tile, 512 blocks, LDS 48 KB dbuf -> 3 blocks/CU. stage(t+1) in flight during
// compute(t); measured ~-2 us vs single-buffered (R6).
__global__ __launch_bounds__(256, 3) void out_gemm(
    const bf16* __restrict__ A, const bf16* __restrict__ Bm,
    const float* __restrict__ bias, float* __restrict__ C) {
  __shared__ alignas(16) bf16 sA[2][64 * 64];
  __shared__ alignas(16) bf16 sB[2][128 * 64];
  const int tid = threadIdx.x;
  const int wave = tid >> 6, lane = tid & 63;
  const int quad = lane >> 4, l16 = lane & 15;
  const int col0w = wave * 32;
  const int rowA0 = blockIdx.x * 64, rowB0 = blockIdx.y * 128;

  f32x4 acc[4][2];
#pragma unroll
  for (int i = 0; i < 4; i++)
#pragma unroll
    for (int j = 0; j < 2; j++) acc[i][j] = (f32x4){0.f, 0.f, 0.f, 0.f};

  const int srow = lane >> 3;
  const int scol = ((lane & 7) ^ srow) * 8;

  auto stage = [&](int kt, int buf) {
#pragma unroll
    for (int i = 0; i < 2; i++) {
      const int r = i * 32 + wave * 8;
      gld_lds16(A + (size_t)(rowA0 + r + srow) * DM + kt * 64 + scol, &sA[buf][r * 64]);
    }
#pragma unroll
    for (int i = 0; i < 4; i++) {
      const int r = i * 32 + wave * 8;
      gld_lds16(Bm + (size_t)(rowB0 + r + srow) * DM + kt * 64 + scol, &sB[buf][r * 64]);
    }
  };

  stage(0, 0);
  for (int t = 0; t < 16; ++t) {
    __syncthreads();  // buf[t&1] loads complete; buf[t^1] free to overwrite
    if (t + 1 < 16) stage(t + 1, (t + 1) & 1);
    const bf16* cA = sA[t & 1];
    const bf16* cB = sB[t & 1];
#pragma unroll
    for (int kk = 0; kk < 64; kk += 32) {
      bf16x8 aF[4], bF[2];
      const int slot = (((kk >> 3) + quad) ^ (l16 & 7)) << 3;
#pragma unroll
      for (int mt = 0; mt < 4; mt++)
        aF[mt] = *(const bf16x8*)&cA[(mt * 16 + l16) * 64 + slot];
#pragma unroll
      for (int nt = 0; nt < 2; nt++)
        bF[nt] = *(const bf16x8*)&cB[(col0w + nt * 16 + l16) * 64 + slot];
#pragma unroll
      for (int mt = 0; mt < 4; mt++)
#pragma unroll
        for (int nt = 0; nt < 2; nt++)
          acc[mt][nt] = __builtin_amdgcn_mfma_f32_16x16x32_bf16(aF[mt], bF[nt], acc[mt][nt], 0, 0, 0);
    }
  }

#pragma unroll
  for (int mt = 0; mt < 4; mt++) {
#pragma unroll
    for (int nt = 0; nt < 2; nt++) {
#pragma unroll
      for (int r = 0; r < 4; r++) {
        const int row = rowA0 + mt * 16 + quad * 4 + r;
        const int col = rowB0 + col0w + nt * 16 + l16;
        C[(size_t)row * DM + col] = acc[mt][nt][r] + bias[col];
      }
    }
  }
}

// ============ Flash attention v3 (final): 32x32 MFMA + in-register softmax ============
// Proven 48.7-50.2 us / ~700 TF. Structure experiments all neutral-to-worse:
// R1 smaller tile (58), R4 V-direct-L2 (75), R5 in-block KV-split 2x occ (49.0),
// R7 QBLK=256 8-wave share (53.4) -> v3 is the local optimum of this family.
// Counter-validated model: latency-chain-bound (per-wave serial chain ~1500+ cyc,
// 2 independent chains/SIMD -> MFMA ~27%, VALU ~33% as measured).
// grid (32 hb, 16 qt) = 512 blocks -> 2 blocks/CU; K+V per (b,h) 512 KB, 4 hb/XCD ->
// 2 MB < 4 MB L2 (hb = linear-id mod 8 pins XCD).
__global__ __launch_bounds__(256, 2) void attn(
    const bf16* __restrict__ Q, const bf16* __restrict__ Kq,
    const bf16* __restrict__ VT, bf16* __restrict__ O) {
  __shared__ alignas(16) bf16 sK[2][64 * 64];
  __shared__ alignas(16) bf16 sV[2][64 * 64];   // V^T tile: [dh=64][seq 64]
  const int tid = threadIdx.x, wave = tid >> 6, lane = tid & 63;
  const int l32 = lane & 31, half = lane >> 5;
  const int hb = blockIdx.x, qt = blockIdx.y;
  const int h = hb & 15, b = hb >> 4;

  const bf16* Qg = Q + (size_t)(b * SQ + qt * 128 + wave * 32) * DM + h * DH;
  const bf16* Kg = Kq + (size_t)(b * SQ) * DM + h * DH;
  const bf16* Vg = VT + (size_t)(h * DH) * MTOT + b * SQ;

  const int srow = lane >> 3, scol = ((lane & 7) ^ srow) * 8;   // 64-wide rows, swizzled

  auto stageKV = [&](int t, int buf) {
#pragma unroll
    for (int i = 0; i < 2; i++) {
      const int r = (wave * 2 + i) * 8;
      gld_lds16(Kg + (size_t)(t * 64 + r + srow) * DM + scol, &sK[buf][r * 64]);
      gld_lds16(Vg + (size_t)(r + srow) * MTOT + t * 64 + scol, &sV[buf][r * 64]);
    }
  };

  // Q as MFMA B-fragment: n=q=lane&31 (row of Q), k = kk*16 + half*8 + j (contiguous 16B)
  bf16x8 qF[4];
#pragma unroll
  for (int kk = 0; kk < 4; kk++)
    qF[kk] = *(const bf16x8*)(Qg + (size_t)l32 * DM + kk * 16 + half * 8);

  f32x16 o_acc[2];
#pragma unroll
  for (int nd = 0; nd < 2; nd++)
#pragma unroll
    for (int i = 0; i < 16; i++) o_acc[nd][i] = 0.f;
  f32x4 lsum4 = (f32x4){0.f, 0.f, 0.f, 0.f};

  stageKV(0, 0);
  for (int t = 0; t < 32; ++t) {
    __syncthreads();  // sK/sV[t&1] ready (staged during t-1's compute)
    if (t + 1 < 32) stageKV(t + 1, (t + 1) & 1);
    const bf16* cK = sK[t & 1];
    const bf16* cV = sV[t & 1];
    const int sw7 = l32 & 7;  // LDS swizzle row bits (row&7 == l32&7 for 32-aligned rows)

    // ---- S^T = K*Q^T: A = K[kv-block 32][k 16] from LDS, B = qF (registers) ----
    f32x16 sacc[2];
#pragma unroll
    for (int nt = 0; nt < 2; nt++)
#pragma unroll
      for (int i = 0; i < 16; i++) sacc[nt][i] = 0.f;

    bf16x8 kf[2][4];
#pragma unroll
    for (int nt = 0; nt < 2; nt++)
#pragma unroll
      for (int kk = 0; kk < 4; kk++)
        kf[nt][kk] = *(const bf16x8*)&cK[(nt * 32 + l32) * 64 + (((kk * 2 + half) ^ sw7) << 3)];
    __builtin_amdgcn_s_setprio(1);
#pragma unroll
    for (int nt = 0; nt < 2; nt++)
#pragma unroll
      for (int kk = 0; kk < 4; kk++)
        sacc[nt] = __builtin_amdgcn_mfma_f32_32x32x16_bf16(kf[nt][kk], qF[kk], sacc[nt], 0, 0, 0);
    __builtin_amdgcn_s_setprio(0);

    // ---- per kv-block: exp2 + in-register P pack (T12) + PV ----
#pragma unroll
    for (int nt = 0; nt < 2; nt++) {
      float p[16];
#pragma unroll
      for (int i = 0; i < 16; i++) {
        p[i] = __builtin_amdgcn_exp2f(sacc[nt][i]);
        lsum4[i & 3] += p[i];   // 4 parallel dep chains
      }
      unsigned int w[8];
#pragma unroll
      for (int i = 0; i < 8; i++)
        asm("v_cvt_pk_bf16_f32 %0, %1, %2" : "=v"(w[i]) : "v"(p[2 * i]), "v"(p[2 * i + 1]));
      // swap pairs (w0,w2),(w1,w3): words land IN ORDER as B-frag of k-step 2*nt;
      // (w4,w6),(w5,w7) -> k-step 2*nt+1.  (verified lane map R3)
      asm("v_permlane32_swap_b32 %0, %1" : "+v"(w[0]), "+v"(w[2]));
      asm("v_permlane32_swap_b32 %0, %1" : "+v"(w[1]), "+v"(w[3]));
      asm("v_permlane32_swap_b32 %0, %1" : "+v"(w[4]), "+v"(w[6]));
      asm("v_permlane32_swap_b32 %0, %1" : "+v"(w[5]), "+v"(w[7]));
#pragma unroll
      for (int s = 0; s < 2; s++) {
        const u32x4 pw = (s == 0) ? (u32x4){w[0], w[1], w[2], w[3]}
                                  : (u32x4){w[4], w[5], w[6], w[7]};
        const bf16x8 pb = __builtin_bit_cast(bf16x8, pw);
        const int ks = nt * 2 + s;  // kv k-step 0..3 within the 64-kv tile
        bf16x8 vf[2];
#pragma unroll
        for (int nd = 0; nd < 2; nd++)
          vf[nd] = *(const bf16x8*)&cV[(nd * 32 + l32) * 64 + (((ks * 2 + half) ^ sw7) << 3)];
        __builtin_amdgcn_s_setprio(1);
#pragma unroll
        for (int nd = 0; nd < 2; nd++)
          o_acc[nd] = __builtin_amdgcn_mfma_f32_32x32x16_bf16(vf[nd], pb, o_acc[nd], 0, 0, 0);
        __builtin_amdgcn_s_setprio(0);
      }
    }
  }

  // l[q] = own-half partial + other-half partial (lane^32 holds same q, other kv half)
  const float lsum = (lsum4[0] + lsum4[1]) + (lsum4[2] + lsum4[3]);
  const float lother = __shfl(lsum, lane ^ 32, 64);
  const float inv = 1.0f / (lsum + lother);

  // O^T C-layout: lane holds col q=l32 (one O row!), d = nd*32 + 8*g + 4*half + r
  bf16* Op = O + (size_t)(b * SQ + qt * 128 + wave * 32 + l32) * DM + h * DH;
#pragma unroll
  for (int nd = 0; nd < 2; nd++) {
#pragma unroll
    for (int g = 0; g < 4; g++) {
      bf16x4 ov;
#pragma unroll
      for (int r = 0; r < 4; r++) ov[r] = (bf16)(o_acc[nd][g * 4 + r] * inv);
      *(bf16x4*)(Op + nd * 32 + g * 8 + half * 4) = ov;
    }
  }
}

extern "C" void kernel_launch(void* const* d_in, const int* in_sizes, int n_in,
                              void* d_out, int out_size, void* d_ws, size_t ws_size,
                              hipStream_t stream) {
  // Reference dtypes: ALL inputs float32, output float32. Internal compute bf16.
  const float* x  = (const float*)d_in[0];
  const float* Wq = (const float*)d_in[1];
  const float* bq = (const float*)d_in[2];
  const float* Wk = (const float*)d_in[3];
  const float* bk = (const float*)d_in[4];
  const float* Wv = (const float*)d_in[5];
  const float* bv = (const float*)d_in[6];
  const float* Wo = (const float*)d_in[7];
  const float* bo = (const float*)d_in[8];
  float* out = (float*)d_out;

  bf16* ws   = (bf16*)d_ws;
  bf16* xb   = ws;                          // [4096][1024]
  bf16* Wqb  = ws + (size_t)MTOT * DM;
  bf16* Wkb  = Wqb + (size_t)DM * DM;
  bf16* Wvb  = Wkb + (size_t)DM * DM;
  bf16* Wob  = Wvb + (size_t)DM * DM;
  bf16* Qw   = Wob + (size_t)DM * DM;       // [4096][1024]  (pre-scaled by QSCALE)
  bf16* Kw   = Qw + (size_t)MTOT * DM;      // [4096][1024]
  bf16* VTw  = Kw + (size_t)MTOT * DM;      // [1024][4096]  (V transposed)
  bf16* Cw   = VTw + (size_t)MTOT * DM;     // [4096][1024]  (context)

  const dim3 blk(256);
  // 4096 blocks x 256 thr x 8 elts == 8M elems exactly (4 x 1M weights + 4M x)
  cvt5<<<dim3((4 * DM * DM + MTOT * DM) / 2048, 1), blk, 0, stream>>>(
      Wq, Wk, Wv, Wo, x, Wqb, Wkb, Wvb, Wob, xb);
  qkv_gemm<<<dim3(32, 8, 3), blk, 0, stream>>>(xb, Wqb, Wkb, Wvb, bq, bk, bv, Qw, Kw, VTw);
  attn<<<dim3(NH * NB, SQ / 128), blk, 0, stream>>>(Qw, Kw, VTw, Cw);
  out_gemm<<<dim3(MTOT / 64, DM / 128), blk, 0, stream>>>(Cw, Wob, bo, out);
}

// Round 10
// 179.169 us; speedup vs baseline: 1.0208x; 1.0108x over previous
//
#include <hip/hip_runtime.h>
#include <hip/hip_bf16.h>

typedef __bf16 bf16;
typedef __bf16 bf16x8 __attribute__((ext_vector_type(8)));
typedef __bf16 bf16x4 __attribute__((ext_vector_type(4)));
typedef float f32x4 __attribute__((ext_vector_type(4)));
typedef float f32x16 __attribute__((ext_vector_type(16)));
typedef unsigned int u32x4 __attribute__((ext_vector_type(4)));

constexpr int DM = 1024, NH = 16, DH = 64, NB = 2, SQ = 2048;
constexpr int MTOT = NB * SQ;  // 4096
// Q is pre-scaled by 1/sqrt(DH) * log2(e) so attn does bare exp2(S).
constexpr float QSCALE = 0.125f * 1.44269504088896f;

// async global->LDS, 16B per lane; LDS dest is wave-uniform base + lane*16 (HW rule)
__device__ __forceinline__ void gld_lds16(const bf16* g, bf16* l) {
  __builtin_amdgcn_global_load_lds(
      (const __attribute__((address_space(1))) void*)g,
      (__attribute__((address_space(3))) void*)l, 16, 0, 0);
}

// ============ fp32 -> bf16 conversion: 4x W (1M elts each) + x (4M elts) ============
// 8 elems/thread (2x float4 read + one 16B bf16x8 store = full-width coalescing).
// 4096 blocks x 256 thr x 8 = 8M elems exactly; W arrays = 512 blocks each, no straddle.
__global__ __launch_bounds__(256) void cvt5(
    const float* __restrict__ s0, const float* __restrict__ s1,
    const float* __restrict__ s2, const float* __restrict__ s3,
    const float* __restrict__ s4,
    bf16* __restrict__ d0, bf16* __restrict__ d1, bf16* __restrict__ d2,
    bf16* __restrict__ d3, bf16* __restrict__ d4) {
  const int idx = (blockIdx.x * 256 + threadIdx.x) * 8;
  const float* src; bf16* dst; int off;
  if (idx < 4 * DM * DM) {               // DM*DM == 2^20
    off = idx & (DM * DM - 1);
    switch (idx >> 20) {
      case 0: src = s0; dst = d0; break;
      case 1: src = s1; dst = d1; break;
      case 2: src = s2; dst = d2; break;
      default: src = s3; dst = d3; break;
    }
  } else {
    src = s4; dst = d4; off = idx - 4 * DM * DM;
  }
  const float4 a = *(const float4*)(src + off);
  const float4 b = *(const float4*)(src + off + 4);
  *(bf16x8*)(dst + off) = (bf16x8){(bf16)a.x, (bf16)a.y, (bf16)a.z, (bf16)a.w,
                                   (bf16)b.x, (bf16)b.y, (bf16)b.z, (bf16)b.w};
}

// ======== GEMM-NT tile body (single-buffered, m97-proven): qkv only ========
// 128x128 tile, BK=64, 256 threads (4 waves), 32 KB LDS, (256,4) best-measured.
// LDS XOR-swizzled: 16B-chunk c of row r at slot c^(r&7) -> ds_read_b128 conflict-free.
template <typename OutT>
__device__ __forceinline__ void gemm_tile128(
    const bf16* __restrict__ A, const bf16* __restrict__ Bm,
    const float* __restrict__ bias, OutT* __restrict__ C,
    int rowA0, int rowB0, int N, int K, bool bias_row, float cscale,
    bf16* sA, bf16* sB) {
  const int tid = threadIdx.x;
  const int wave = tid >> 6, lane = tid & 63;
  const int quad = lane >> 4, l16 = lane & 15;
  const int row0w = (wave >> 1) * 64;
  const int col0w = (wave & 1) * 64;

  f32x4 acc[4][4];
#pragma unroll
  for (int i = 0; i < 4; i++)
#pragma unroll
    for (int j = 0; j < 4; j++) acc[i][j] = (f32x4){0.f, 0.f, 0.f, 0.f};

  const int srow = lane >> 3;                         // 0..7
  const int scol = ((lane & 7) ^ srow) * 8;           // swizzled global chunk

  for (int kt = 0; kt < K; kt += 64) {
#pragma unroll
    for (int i = 0; i < 4; i++) {
      const int r = i * 32 + wave * 8;
      gld_lds16(A + (size_t)(rowA0 + r + srow) * K + kt + scol, &sA[r * 64]);
      gld_lds16(Bm + (size_t)(rowB0 + r + srow) * K + kt + scol, &sB[r * 64]);
    }
    __syncthreads();  // drains vmcnt for global_load_lds
#pragma unroll
    for (int kk = 0; kk < 64; kk += 32) {
      bf16x8 aF[4], bF[4];
      const int slot = (((kk >> 3) + quad) ^ (l16 & 7)) << 3;
#pragma unroll
      for (int mt = 0; mt < 4; mt++)
        aF[mt] = *(const bf16x8*)&sA[(row0w + mt * 16 + l16) * 64 + slot];
#pragma unroll
      for (int nt = 0; nt < 4; nt++)
        bF[nt] = *(const bf16x8*)&sB[(col0w + nt * 16 + l16) * 64 + slot];
#pragma unroll
      for (int mt = 0; mt < 4; mt++)
#pragma unroll
        for (int nt = 0; nt < 4; nt++)
          acc[mt][nt] = __builtin_amdgcn_mfma_f32_16x16x32_bf16(aF[mt], bF[nt], acc[mt][nt], 0, 0, 0);
    }
    __syncthreads();
  }

  // epilogue: C/D layout col=lane&15, row=quad*4+reg (verified m89/m91)
#pragma unroll
  for (int mt = 0; mt < 4; mt++) {
#pragma unroll
    for (int nt = 0; nt < 4; nt++) {
#pragma unroll
      for (int r = 0; r < 4; r++) {
        const int row = rowA0 + row0w + mt * 16 + quad * 4 + r;
        const int col = rowB0 + col0w + nt * 16 + l16;
        const float bb = bias_row ? bias[row] : bias[col];
        C[(size_t)row * N + col] = (OutT)((acc[mt][nt][r] + bb) * cscale);
      }
    }
  }
}

// Fused Q/K/V^T projection: grid (32, 8, 3). z=0 -> Q (pre-scaled), z=1 -> K, z=2 -> V^T.
__global__ __launch_bounds__(256, 4) void qkv_gemm(
    const bf16* __restrict__ xb, const bf16* __restrict__ Wqb,
    const bf16* __restrict__ Wkb, const bf16* __restrict__ Wvb,
    const float* __restrict__ bq, const float* __restrict__ bk,
    const float* __restrict__ bv,
    bf16* __restrict__ Qw, bf16* __restrict__ Kw, bf16* __restrict__ VTw) {
  __shared__ alignas(16) bf16 sA[128 * 64];
  __shared__ alignas(16) bf16 sB[128 * 64];
  if (blockIdx.z == 0) {
    gemm_tile128<bf16>(xb, Wqb, bq, Qw, blockIdx.x * 128, blockIdx.y * 128, DM, DM, false, QSCALE, sA, sB);
  } else if (blockIdx.z == 1) {
    gemm_tile128<bf16>(xb, Wkb, bk, Kw, blockIdx.x * 128, blockIdx.y * 128, DM, DM, false, 1.0f, sA, sB);
  } else {
    // VT[n][m] = sum_k Wv[n][k] x[m][k] + bv[n]  (swapped operands -> V^T layout directly)
    const int id = blockIdx.y * 32 + blockIdx.x;  // 0..255
    gemm_tile128<bf16>(Wvb, xb, bv, VTw, (id >> 5) * 128, (id & 31) * 128, MTOT, DM, true, 1.0f, sA, sB);
  }
}

// ======== Output projection (R6): double-buffered prefetch K-loop, 1 barrier/step ========
// 64x128 tile, 512 blocks, LDS 48 KB dbuf -> 3 blocks/CU. stage(t+1) in flight during
// compute(t); measured ~-2 us vs single-buffered (R6).
__global__ __launch_bounds__(256, 3) void out_gemm(
    const bf16* __restrict__ A, const bf16* __restrict__ Bm,
    const float* __restrict__ bias, float* __restrict__ C) {
  __shared__ alignas(16) bf16 sA[2][64 * 64];
  __shared__ alignas(16) bf16 sB[2][128 * 64];
  const int tid = threadIdx.x;
  const int wave = tid >> 6, lane = tid & 63;
  const int quad = lane >> 4, l16 = lane & 15;
  const int col0w = wave * 32;
  const int rowA0 = blockIdx.x * 64, rowB0 = blockIdx.y * 128;

  f32x4 acc[4][2];
#pragma unroll
  for (int i = 0; i < 4; i++)
#pragma unroll
    for (int j = 0; j < 2; j++) acc[i][j] = (f32x4){0.f, 0.f, 0.f, 0.f};

  const int srow = lane >> 3;
  const int scol = ((lane & 7) ^ srow) * 8;

  auto stage = [&](int kt, int buf) {
#pragma unroll
    for (int i = 0; i < 2; i++) {
      const int r = i * 32 + wave * 8;
      gld_lds16(A + (size_t)(rowA0 + r + srow) * DM + kt * 64 + scol, &sA[buf][r * 64]);
    }
#pragma unroll
    for (int i = 0; i < 4; i++) {
      const int r = i * 32 + wave * 8;
      gld_lds16(Bm + (size_t)(rowB0 + r + srow) * DM + kt * 64 + scol, &sB[buf][r * 64]);
    }
  };

  stage(0, 0);
  for (int t = 0; t < 16; ++t) {
    __syncthreads();  // buf[t&1] loads complete; buf[t^1] free to overwrite
    if (t + 1 < 16) stage(t + 1, (t + 1) & 1);
    const bf16* cA = sA[t & 1];
    const bf16* cB = sB[t & 1];
#pragma unroll
    for (int kk = 0; kk < 64; kk += 32) {
      bf16x8 aF[4], bF[2];
      const int slot = (((kk >> 3) + quad) ^ (l16 & 7)) << 3;
#pragma unroll
      for (int mt = 0; mt < 4; mt++)
        aF[mt] = *(const bf16x8*)&cA[(mt * 16 + l16) * 64 + slot];
#pragma unroll
      for (int nt = 0; nt < 2; nt++)
        bF[nt] = *(const bf16x8*)&cB[(col0w + nt * 16 + l16) * 64 + slot];
#pragma unroll
      for (int mt = 0; mt < 4; mt++)
#pragma unroll
        for (int nt = 0; nt < 2; nt++)
          acc[mt][nt] = __builtin_amdgcn_mfma_f32_16x16x32_bf16(aF[mt], bF[nt], acc[mt][nt], 0, 0, 0);
    }
  }

#pragma unroll
  for (int mt = 0; mt < 4; mt++) {
#pragma unroll
    for (int nt = 0; nt < 2; nt++) {
#pragma unroll
      for (int r = 0; r < 4; r++) {
        const int row = rowA0 + mt * 16 + quad * 4 + r;
        const int col = rowB0 + col0w + nt * 16 + l16;
        C[(size_t)row * DM + col] = acc[mt][nt][r] + bias[col];
      }
    }
  }
}

// ============ Flash attention v8: v3 + ones-MFMA rowsum (restored from R0) ============
// v3 body (proven 48.7-49.2 us). R9 fix: the R2 32x32 rewrite dropped R0's ones-MFMA
// rowsum and used 32 scalar VALU adds/lane/tile on the exp2-dependent critical path.
// Restored in 32x32 form: l_acc = mfma(onesA, pb) — 4 MFMAs/tile on the idle MFMA pipe,
// D[i][q] = sum_k P_bf16[k][q] (full k=16 slice, BOTH lane halves) -> epilogue needs NO
// lane^32 shfl, and normalization uses exactly the bf16 P that PV multiplies.
// grid (32 hb, 16 qt) = 512 blocks -> 2 blocks/CU; K+V per (b,h) 512 KB, 4 hb/XCD ->
// 2 MB < 4 MB L2 (hb = linear-id mod 8 pins XCD).
__global__ __launch_bounds__(256, 2) void attn(
    const bf16* __restrict__ Q, const bf16* __restrict__ Kq,
    const bf16* __restrict__ VT, bf16* __restrict__ O) {
  __shared__ alignas(16) bf16 sK[2][64 * 64];
  __shared__ alignas(16) bf16 sV[2][64 * 64];   // V^T tile: [dh=64][seq 64]
  const int tid = threadIdx.x, wave = tid >> 6, lane = tid & 63;
  const int l32 = lane & 31, half = lane >> 5;
  const int hb = blockIdx.x, qt = blockIdx.y;
  const int h = hb & 15, b = hb >> 4;

  const bf16* Qg = Q + (size_t)(b * SQ + qt * 128 + wave * 32) * DM + h * DH;
  const bf16* Kg = Kq + (size_t)(b * SQ) * DM + h * DH;
  const bf16* Vg = VT + (size_t)(h * DH) * MTOT + b * SQ;

  const int srow = lane >> 3, scol = ((lane & 7) ^ srow) * 8;   // 64-wide rows, swizzled

  auto stageKV = [&](int t, int buf) {
#pragma unroll
    for (int i = 0; i < 2; i++) {
      const int r = (wave * 2 + i) * 8;
      gld_lds16(Kg + (size_t)(t * 64 + r + srow) * DM + scol, &sK[buf][r * 64]);
      gld_lds16(Vg + (size_t)(r + srow) * MTOT + t * 64 + scol, &sV[buf][r * 64]);
    }
  };

  // Q as MFMA B-fragment: n=q=lane&31 (row of Q), k = kk*16 + half*8 + j (contiguous 16B)
  bf16x8 qF[4];
#pragma unroll
  for (int kk = 0; kk < 4; kk++)
    qF[kk] = *(const bf16x8*)(Qg + (size_t)l32 * DM + kk * 16 + half * 8);

  bf16x8 onesF;
#pragma unroll
  for (int i = 0; i < 8; i++) onesF[i] = (bf16)1.0f;

  f32x16 o_acc[2];
  f32x16 l_acc;
#pragma unroll
  for (int i = 0; i < 16; i++) { o_acc[0][i] = 0.f; o_acc[1][i] = 0.f; l_acc[i] = 0.f; }

  stageKV(0, 0);
  for (int t = 0; t < 32; ++t) {
    __syncthreads();  // sK/sV[t&1] ready (staged during t-1's compute)
    if (t + 1 < 32) stageKV(t + 1, (t + 1) & 1);
    const bf16* cK = sK[t & 1];
    const bf16* cV = sV[t & 1];
    const int sw7 = l32 & 7;  // LDS swizzle row bits (row&7 == l32&7 for 32-aligned rows)

    // ---- S^T = K*Q^T: A = K[kv-block 32][k 16] from LDS, B = qF (registers) ----
    f32x16 sacc[2];
#pragma unroll
    for (int nt = 0; nt < 2; nt++)
#pragma unroll
      for (int i = 0; i < 16; i++) sacc[nt][i] = 0.f;

    bf16x8 kf[2][4];
#pragma unroll
    for (int nt = 0; nt < 2; nt++)
#pragma unroll
      for (int kk = 0; kk < 4; kk++)
        kf[nt][kk] = *(const bf16x8*)&cK[(nt * 32 + l32) * 64 + (((kk * 2 + half) ^ sw7) << 3)];
    __builtin_amdgcn_s_setprio(1);
#pragma unroll
    for (int nt = 0; nt < 2; nt++)
#pragma unroll
      for (int kk = 0; kk < 4; kk++)
        sacc[nt] = __builtin_amdgcn_mfma_f32_32x32x16_bf16(kf[nt][kk], qF[kk], sacc[nt], 0, 0, 0);
    __builtin_amdgcn_s_setprio(0);

    // ---- per kv-block: exp2 + in-register P pack (T12) + PV + l via ones-MFMA ----
#pragma unroll
    for (int nt = 0; nt < 2; nt++) {
      float p[16];
#pragma unroll
      for (int i = 0; i < 16; i++)
        p[i] = __builtin_amdgcn_exp2f(sacc[nt][i]);
      unsigned int w[8];
#pragma unroll
      for (int i = 0; i < 8; i++)
        asm("v_cvt_pk_bf16_f32 %0, %1, %2" : "=v"(w[i]) : "v"(p[2 * i]), "v"(p[2 * i + 1]));
      // swap pairs (w0,w2),(w1,w3): words land IN ORDER as B-frag of k-step 2*nt;
      // (w4,w6),(w5,w7) -> k-step 2*nt+1.  (verified lane map R3)
      asm("v_permlane32_swap_b32 %0, %1" : "+v"(w[0]), "+v"(w[2]));
      asm("v_permlane32_swap_b32 %0, %1" : "+v"(w[1]), "+v"(w[3]));
      asm("v_permlane32_swap_b32 %0, %1" : "+v"(w[4]), "+v"(w[6]));
      asm("v_permlane32_swap_b32 %0, %1" : "+v"(w[5]), "+v"(w[7]));
#pragma unroll
      for (int s = 0; s < 2; s++) {
        const u32x4 pw = (s == 0) ? (u32x4){w[0], w[1], w[2], w[3]}
                                  : (u32x4){w[4], w[5], w[6], w[7]};
        const bf16x8 pb = __builtin_bit_cast(bf16x8, pw);
        const int ks = nt * 2 + s;  // kv k-step 0..3 within the 64-kv tile
        bf16x8 vf[2];
#pragma unroll
        for (int nd = 0; nd < 2; nd++)
          vf[nd] = *(const bf16x8*)&cV[(nd * 32 + l32) * 64 + (((ks * 2 + half) ^ sw7) << 3)];
        __builtin_amdgcn_s_setprio(1);
#pragma unroll
        for (int nd = 0; nd < 2; nd++)
          o_acc[nd] = __builtin_amdgcn_mfma_f32_32x32x16_bf16(vf[nd], pb, o_acc[nd], 0, 0, 0);
        // rowsum: D[i][q] = sum_k 1*P[k][q]; full k=16 slice -> no lane-half combine
        l_acc = __builtin_amdgcn_mfma_f32_32x32x16_bf16(onesF, pb, l_acc, 0, 0, 0);
        __builtin_amdgcn_s_setprio(0);
      }
    }
  }

  // all 16 l_acc regs hold l[q=l32]; no shfl needed (k-sum spans both lane halves)
  const float inv = 1.0f / l_acc[0];

  // O^T C-layout: lane holds col q=l32 (one O row!), d = nd*32 + 8*g + 4*half + r
  bf16* Op = O + (size_t)(b * SQ + qt * 128 + wave * 32 + l32) * DM + h * DH;
#pragma unroll
  for (int nd = 0; nd < 2; nd++) {
#pragma unroll
    for (int g = 0; g < 4; g++) {
      bf16x4 ov;
#pragma unroll
      for (int r = 0; r < 4; r++) ov[r] = (bf16)(o_acc[nd][g * 4 + r] * inv);
      *(bf16x4*)(Op + nd * 32 + g * 8 + half * 4) = ov;
    }
  }
}

extern "C" void kernel_launch(void* const* d_in, const int* in_sizes, int n_in,
                              void* d_out, int out_size, void* d_ws, size_t ws_size,
                              hipStream_t stream) {
  // Reference dtypes: ALL inputs float32, output float32. Internal compute bf16.
  const float* x  = (const float*)d_in[0];
  const float* Wq = (const float*)d_in[1];
  const float* bq = (const float*)d_in[2];
  const float* Wk = (const float*)d_in[3];
  const float* bk = (const float*)d_in[4];
  const float* Wv = (const float*)d_in[5];
  const float* bv = (const float*)d_in[6];
  const float* Wo = (const float*)d_in[7];
  const float* bo = (const float*)d_in[8];
  float* out = (float*)d_out;

  bf16* ws   = (bf16*)d_ws;
  bf16* xb   = ws;                          // [4096][1024]
  bf16* Wqb  = ws + (size_t)MTOT * DM;
  bf16* Wkb  = Wqb + (size_t)DM * DM;
  bf16* Wvb  = Wkb + (size_t)DM * DM;
  bf16* Wob  = Wvb + (size_t)DM * DM;
  bf16* Qw   = Wob + (size_t)DM * DM;       // [4096][1024]  (pre-scaled by QSCALE)
  bf16* Kw   = Qw + (size_t)MTOT * DM;      // [4096][1024]
  bf16* VTw  = Kw + (size_t)MTOT * DM;      // [1024][4096]  (V transposed)
  bf16* Cw   = VTw + (size_t)MTOT * DM;     // [4096][1024]  (context)

  const dim3 blk(256);
  // 4096 blocks x 256 thr x 8 elts == 8M elems exactly (4 x 1M weights + 4M x)
  cvt5<<<dim3((4 * DM * DM + MTOT * DM) / 2048, 1), blk, 0, stream>>>(
      Wq, Wk, Wv, Wo, x, Wqb, Wkb, Wvb, Wob, xb);
  qkv_gemm<<<dim3(32, 8, 3), blk, 0, stream>>>(xb, Wqb, Wkb, Wvb, bq, bk, bv, Qw, Kw, VTw);
  attn<<<dim3(NH * NB, SQ / 128), blk, 0, stream>>>(Qw, Kw, VTw, Cw);
  out_gemm<<<dim3(MTOT / 64, DM / 128), blk, 0, stream>>>(Cw, Wob, bo, out);
}